// Round 1
// baseline (307.130 us; speedup 1.0000x reference)
//
#include <hip/hip_runtime.h>
#include <math.h>

// dims: B=16 K=1 NC=64 NR=4 RF=4 L=8 M=256 N=1024 BS_TDD=16 RIS_TDD=16
static constexpr double TWO_PI_D = 6.283185307179586476925287;

// workspace offsets (floats)
static constexpr size_t OFF_THRE = 0;          // theta_re [l][c][n]   524288
static constexpr size_t OFF_THIM = 524288;     // theta_im             524288
static constexpr size_t OFF_FRE  = 1048576;    // F_re [l][c][f][m]    524288
static constexpr size_t OFF_FIM  = 1572864;    // F_im                 524288
static constexpr size_t OFF_WT   = 2097152;    // WT [l][c][n][f][2]   4194304
static constexpr size_t OFF_Y0   = 6291456;    // y0 [b][l][c][rf][2]  262144
static constexpr size_t OFF_X    = 6553600;    // x  [b][c][rf][t]     262144
static constexpr size_t WS_FLOATS = 6815744;   // ~27.3 MB

__device__ __forceinline__ double fm_of(int c){
  return ((double)(c + 1) - 32.5) * (1.0e9 / 64.0) + 1.0e11;
}

__global__ __launch_bounds__(256) void k_theta(
    const float* __restrict__ P1, const float* __restrict__ P2,
    const float* __restrict__ PT, float* __restrict__ tre, float* __restrict__ tim)
{
  int t = blockIdx.x * 256 + threadIdx.x;       // (l*64+c)*1024+n
  int n = t & 1023, c = (t >> 10) & 63, l = t >> 16;
  float p1 = P1[l * 1024 + n], p2 = P2[l * 1024 + n];
  const float TWO_PI_F = 6.2831855f, SEG_F = 3.1415927f;
  int k1 = (int)floorf((TWO_PI_F * p1) / SEG_F);   // BIT=1 -> seg=pi -> exp(i*k*pi)=+-1
  int k2 = (int)floorf((TWO_PI_F * p2) / SEG_F);
  float s = ((k1 + k2) & 1) ? -1.f : 1.f;
  float a1 = 5.0e-9f / (1.f + expf(-PT[l * 16 + (n >> 6)]));  // MAX_DELAY*sigmoid
  double arg = TWO_PI_D * fm_of(c) * (double)a1;
  double sa, ca;
  sincos(arg, &sa, &ca);
  tre[t] = s * (float)ca;
  tim[t] = s * (float)sa;
}

__global__ __launch_bounds__(256) void k_F(
    const float* __restrict__ SA, const float* __restrict__ ST,
    float* __restrict__ fre, float* __restrict__ fim)
{
  int t = blockIdx.x * 256 + threadIdx.x;       // ((l*64+c)*4+f)*256+m
  int m = t & 255, f = (t >> 8) & 3, c = (t >> 10) & 63, l = t >> 16;
  float sa_ = SA[(size_t)((l * 64 + c) * 256 + m) * 4 + f];       // S_analog [L][NC][M][RF]
  float st_ = ST[((l * 64 + c) * 16 + (m >> 4)) * 4 + f];         // S_TDD [L][NC][16][RF], m//16
  float bdel = 5.0e-9f / (1.f + expf(-st_));
  double ang = (double)sa_ + TWO_PI_D * fm_of(c) * (double)bdel;
  double sn, cs;
  sincos(ang, &sn, &cs);
  fre[t] = (float)cs * 0.0625f;   // /sqrt(256)
  fim[t] = (float)sn * 0.0625f;
}

// WT[l,c,n,f] = theta[l,c,n] * sum_m H_BR[c,n,m] * F[l,c,m,f]
// block: (c, 32-n chunk). 512 threads = (l, f, mg(8 m-groups of 32), nh(2 n-halves))
__global__ __launch_bounds__(512) void k_W(
    const float* __restrict__ Hre, const float* __restrict__ Him,
    const float* __restrict__ Fre, const float* __restrict__ Fim,
    const float* __restrict__ tre, const float* __restrict__ tim,
    float* __restrict__ WT)
{
  __shared__ __align__(16) float hre[8192];   // [row=(m%32)*8+m/32][col=(n+4*(m/32))&31]
  __shared__ __align__(16) float him[8192];
  __shared__ __align__(16) float2 fld[8192];  // [j=m%32][lf][mg=m/32]
  int bid = blockIdx.x;
  int lidx = (bid & 7) * 256 + (bid >> 3);    // XCD-chunked swizzle: same-c blocks co-XCD
  int c = lidx >> 5, nch = lidx & 31;
  int n0 = nch * 32;
  int tid = threadIdx.x;

  #pragma unroll
  for (int kk = 0; kk < 4; kk++){
    int chunk = tid + 512 * kk;               // 2048 float4 per component
    int n = chunk >> 6;
    int m = (chunk & 63) * 4;
    size_t g = ((size_t)(c * 1024 + n0 + n)) * 256 + m;
    float4 r4 = *(const float4*)(Hre + g);
    float4 i4 = *(const float4*)(Him + g);
    int mg = m >> 5;
    int col = (n + 4 * mg) & 31;
    int row0 = (m & 31) * 8 + mg;
    hre[(row0     ) * 32 + col] = r4.x;
    hre[(row0 +  8) * 32 + col] = r4.y;
    hre[(row0 + 16) * 32 + col] = r4.z;
    hre[(row0 + 24) * 32 + col] = r4.w;
    him[(row0     ) * 32 + col] = i4.x;
    him[(row0 +  8) * 32 + col] = i4.y;
    him[(row0 + 16) * 32 + col] = i4.z;
    him[(row0 + 24) * 32 + col] = i4.w;
  }
  #pragma unroll
  for (int kk = 0; kk < 16; kk++){
    int idx = tid + 512 * kk;                 // 8192 complex F values for this c
    int lf = idx >> 8, m = idx & 255;
    int ll = lf >> 2, ff = lf & 3;
    size_t g = ((size_t)((ll * 64 + c) * 4 + ff)) * 256 + m;
    fld[((m & 31) * 32 + lf) * 8 + (m >> 5)] = make_float2(Fre[g], Fim[g]);
  }
  __syncthreads();

  int nh = tid & 1;
  int mg = (tid >> 1) & 7;
  int f  = (tid >> 4) & 3;
  int l  = tid >> 6;
  int lfg = l * 4 + f;
  int colbase = (nh * 16 + 4 * mg) & 31;

  float aR[16], aI[16];
  #pragma unroll
  for (int i = 0; i < 16; i++){ aR[i] = 0.f; aI[i] = 0.f; }

  for (int j = 0; j < 32; j++){
    float2 fv = fld[(j * 32 + lfg) * 8 + mg];
    const float* hr = hre + (j * 8 + mg) * 32;
    const float* hi = him + (j * 8 + mg) * 32;
    #pragma unroll
    for (int nb = 0; nb < 4; nb++){
      int col = (colbase + nb * 4) & 31;
      float4 h4 = *(const float4*)(hr + col);
      float4 g4 = *(const float4*)(hi + col);
      aR[nb*4+0] += h4.x * fv.x - g4.x * fv.y;  aI[nb*4+0] += h4.x * fv.y + g4.x * fv.x;
      aR[nb*4+1] += h4.y * fv.x - g4.y * fv.y;  aI[nb*4+1] += h4.y * fv.y + g4.y * fv.x;
      aR[nb*4+2] += h4.z * fv.x - g4.z * fv.y;  aI[nb*4+2] += h4.z * fv.y + g4.z * fv.x;
      aR[nb*4+3] += h4.w * fv.x - g4.w * fv.y;  aI[nb*4+3] += h4.w * fv.y + g4.w * fv.x;
    }
  }
  // reduce over mg (tid bits 1..3)
  #pragma unroll
  for (int s = 2; s <= 8; s <<= 1){
    #pragma unroll
    for (int i = 0; i < 16; i++){
      aR[i] += __shfl_xor(aR[i], s);
      aI[i] += __shfl_xor(aI[i], s);
    }
  }
  if (mg == 0){
    #pragma unroll
    for (int i = 0; i < 16; i++){
      int n = n0 + nh * 16 + i;
      size_t tix = (size_t)(l * 64 + c) * 1024 + n;
      float wr = tre[tix], wi = tim[tix];
      float2 o;
      o.x = wr * aR[i] - wi * aI[i];
      o.y = wr * aI[i] + wi * aR[i];
      *(float2*)(WT + tix * 8 + f * 2) = o;
    }
  }
}

// y0[b,l,c,r,f] = sum_n H_RU[b,c,r,n] * WT[l,c,n,f]
// block: (l,c). 256 threads = (b, r, q(4 n-interleaves))
__global__ __launch_bounds__(256) void k_y0(
    const float* __restrict__ Rre, const float* __restrict__ Rim,
    const float* __restrict__ WT, float* __restrict__ Y0)
{
  __shared__ __align__(16) float wt[8192];
  int bid = blockIdx.x;
  int lidx = (bid & 7) * 64 + (bid >> 3);     // same-c blocks co-XCD (H_RU L2 reuse over l)
  int c = lidx >> 3, l = lidx & 7;
  const float* src = WT + (size_t)(l * 64 + c) * 8192;
  #pragma unroll
  for (int kk = 0; kk < 8; kk++){
    int i = (threadIdx.x + 256 * kk) * 4;
    *(float4*)(wt + i) = *(const float4*)(src + i);
  }
  __syncthreads();
  int tid = threadIdx.x;
  int q = tid & 3, r = (tid >> 2) & 3, b = tid >> 4;
  const float* hr = Rre + ((size_t)((b * 64 + c) * 4 + r)) * 1024;
  const float* hi = Rim + ((size_t)((b * 64 + c) * 4 + r)) * 1024;
  float aR[4] = {0,0,0,0}, aI[4] = {0,0,0,0};
  #pragma unroll 4
  for (int i = 0; i < 256; i++){
    int n = i * 4 + q;                         // q-interleave -> bank-distinct WT reads
    float xr = hr[n], xi = hi[n];
    float4 w01 = *(const float4*)(wt + n * 8);
    float4 w23 = *(const float4*)(wt + n * 8 + 4);
    aR[0] += xr * w01.x - xi * w01.y;  aI[0] += xr * w01.y + xi * w01.x;
    aR[1] += xr * w01.z - xi * w01.w;  aI[1] += xr * w01.w + xi * w01.z;
    aR[2] += xr * w23.x - xi * w23.y;  aI[2] += xr * w23.y + xi * w23.x;
    aR[3] += xr * w23.z - xi * w23.w;  aI[3] += xr * w23.w + xi * w23.z;
  }
  #pragma unroll
  for (int s = 1; s < 4; s <<= 1){
    #pragma unroll
    for (int ff = 0; ff < 4; ff++){
      aR[ff] += __shfl_xor(aR[ff], s);
      aI[ff] += __shfl_xor(aI[ff], s);
    }
  }
  if (q == 0){
    float* dst = Y0 + ((size_t)((b * 8 + l) * 64 + c) * 16 + r * 4) * 2;
    float4 o0; o0.x = aR[0]; o0.y = aI[0]; o0.z = aR[1]; o0.w = aI[1];
    float4 o1; o1.x = aR[2]; o1.y = aI[2]; o1.z = aR[3]; o1.w = aI[3];
    *(float4*)(dst)     = o0;
    *(float4*)(dst + 4) = o1;
  }
}

// per (b,l,c) wave: y0 += H_BU*F ; power; noise; scatter into x[b,c,rf,t]
__global__ __launch_bounds__(256) void k_fin(
    const float* __restrict__ Ure, const float* __restrict__ Uim,
    const float* __restrict__ Fre, const float* __restrict__ Fim,
    const float* __restrict__ Y0, const float* __restrict__ nre, const float* __restrict__ nim,
    float* __restrict__ X)
{
  int wid = blockIdx.x * 4 + (threadIdx.x >> 6);  // 8192 = (b,l,c)
  int lane = threadIdx.x & 63;
  int c = wid & 63, l = (wid >> 6) & 7, b = wid >> 9;
  int pair = lane >> 2, q = lane & 3;
  int r = pair >> 2, f = pair & 3;
  const float* ur = Ure + ((size_t)((b * 64 + c) * 4 + r)) * 256;
  const float* ui = Uim + ((size_t)((b * 64 + c) * 4 + r)) * 256;
  const float* fr = Fre + ((size_t)((l * 64 + c) * 4 + f)) * 256;
  const float* fi = Fim + ((size_t)((l * 64 + c) * 4 + f)) * 256;
  float sR = 0.f, sI = 0.f;
  #pragma unroll 4
  for (int mm = 0; mm < 64; mm++){
    int m = q * 64 + mm;
    float ar = ur[m], ai = ui[m], br = fr[m], bi = fi[m];
    sR += ar * br - ai * bi;
    sI += ar * bi + ai * br;
  }
  sR += __shfl_xor(sR, 1); sI += __shfl_xor(sI, 1);
  sR += __shfl_xor(sR, 2); sI += __shfl_xor(sI, 2);
  float2 y0 = *(const float2*)(Y0 + ((size_t)((b * 8 + l) * 64 + c) * 16 + pair) * 2);
  float yR = y0.x + sR, yI = y0.y + sI;
  float p = yR * yR + yI * yI;
  p += __shfl_xor(p, 4); p += __shfl_xor(p, 8);
  p += __shfl_xor(p, 16); p += __shfl_xor(p, 32);
  float sc = sqrtf(p * 0.05f);                 // sqrt(power * snr_lin/2), snr_lin=0.1
  if (q == 0){
    size_t ni = ((size_t)((b * 8 + l) * 64 + c) * 4 + r) * 4 + f;
    float oR = yR + nre[ni] * sc;
    float oI = yI + nim[ni] * sc;
    size_t xb = ((size_t)(b * 64 + c) * 16 + pair) * 16;
    X[xb + l]     = oR;   // t = l      (real half)
    X[xb + 8 + l] = oI;   // t = 8 + l  (imag half)
  }
}

// Parallel Polarized Self-Attention, one block per b. b=16,c=64,hw=256.
__global__ __launch_bounds__(256) void k_psa(
    const float* __restrict__ Xin,
    const float* __restrict__ wv_w, const float* __restrict__ wv_b,
    const float* __restrict__ wq_w, const float* __restrict__ wq_b,
    const float* __restrict__ wz_w, const float* __restrict__ wz_b,
    const float* __restrict__ lnw, const float* __restrict__ lnb,
    const float* __restrict__ sv_w, const float* __restrict__ sv_b,
    const float* __restrict__ sq_w, const float* __restrict__ sq_b,
    float* __restrict__ out)
{
  __shared__ float x[64 * 257];
  __shared__ float buf[256];
  __shared__ float xms[64], xqs[64], chw[64], wcomb[64];
  __shared__ float cwzs[32], swqs[32];
  __shared__ float red4[8];
  int b = blockIdx.x, tid = threadIdx.x;
  const float* xin = Xin + (size_t)b * 16384;
  for (int kk = 0; kk < 64; kk++){
    int i = tid + 256 * kk;
    x[(i >> 8) * 257 + (i & 255)] = xin[i];
  }
  __syncthreads();
  if (tid < 64){                                 // row means
    float s = 0.f;
    for (int n = 0; n < 256; n++) s += x[tid * 257 + n];
    xms[tid] = s * (1.f / 256.f);
  }
  // channel softmax over n
  float lq = wq_b[0];
  for (int cc = 0; cc < 64; cc++) lq += wq_w[cc] * x[cc * 257 + tid];
  float mx = lq;
  for (int s = 1; s < 64; s <<= 1) mx = fmaxf(mx, __shfl_xor(mx, s));
  if ((tid & 63) == 0) red4[tid >> 6] = mx;
  __syncthreads();
  mx = fmaxf(fmaxf(red4[0], red4[1]), fmaxf(red4[2], red4[3]));
  float e = expf(lq - mx);
  float se = e;
  for (int s = 1; s < 64; s <<= 1) se += __shfl_xor(se, s);
  if ((tid & 63) == 0) red4[4 + (tid >> 6)] = se;
  __syncthreads();
  se = red4[4] + red4[5] + red4[6] + red4[7];
  buf[tid] = e / se;                             // cwq[n]
  __syncthreads();
  if (tid < 64){                                 // xq[c] = sum_n x*cwq
    float s = 0.f;
    for (int n = 0; n < 256; n++) s += x[tid * 257 + n] * buf[n];
    xqs[tid] = s;
  }
  __syncthreads();
  if (tid < 32){                                 // cwz[k]
    float s = wv_b[tid];
    for (int cc = 0; cc < 64; cc++) s += wv_w[tid * 64 + cc] * xqs[cc];
    cwzs[tid] = s;
  }
  __syncthreads();
  if (tid < 64){                                 // z, LayerNorm, sigmoid
    float z = wz_b[tid];
    for (int k = 0; k < 32; k++) z += cwzs[k] * wz_w[tid * 32 + k];
    float s1 = z, s2 = z * z;
    for (int s = 1; s < 64; s <<= 1){ s1 += __shfl_xor(s1, s); s2 += __shfl_xor(s2, s); }
    float mu = s1 * (1.f / 64.f);
    float var = s2 * (1.f / 64.f) - mu * mu;
    float zn = (z - mu) * rsqrtf(var + 1e-5f) * lnw[tid] + lnb[tid];
    chw[tid] = 1.f / (1.f + expf(-zn));
  }
  if (tid < 32){                                 // spatial softmax over k
    float s = sq_b[tid];
    for (int cc = 0; cc < 64; cc++) s += sq_w[tid * 64 + cc] * xms[cc];
    float m2 = s;
    for (int st = 1; st < 32; st <<= 1) m2 = fmaxf(m2, __shfl_xor(m2, st));
    float ee = expf(s - m2), ss = ee;
    for (int st = 1; st < 32; st <<= 1) ss += __shfl_xor(ss, st);
    swqs[tid] = ee / ss;
  }
  __syncthreads();
  if (tid < 64){                                 // wcomb[c] = sum_k swq*sv_w
    float s = 0.f;
    for (int k = 0; k < 32; k++) s += swqs[k] * sv_w[k * 64 + tid];
    wcomb[tid] = s;
  }
  __syncthreads();
  float bcomb = 0.f;
  for (int k = 0; k < 32; k++) bcomb += swqs[k] * sv_b[k];
  float sz = bcomb;
  for (int cc = 0; cc < 64; cc++) sz += wcomb[cc] * x[cc * 257 + tid];
  float spw = 1.f / (1.f + expf(-sz));
  buf[tid] = spw;                                // reuse buf (cwq dead)
  __syncthreads();
  for (int kk = 0; kk < 64; kk++){
    int i = tid + 256 * kk;
    int cc = i >> 8, n = i & 255;
    out[(size_t)b * 16384 + i] = (buf[n] + chw[cc]) * x[cc * 257 + n];
  }
}

extern "C" void kernel_launch(void* const* d_in, const int* in_sizes, int n_in,
                              void* d_out, int out_size, void* d_ws, size_t ws_size,
                              hipStream_t stream)
{
  if (ws_size < WS_FLOATS * sizeof(float)) return;  // loud failure via validation
  const float* HBRre = (const float*)d_in[0];
  const float* HBRim = (const float*)d_in[1];
  const float* HRUre = (const float*)d_in[2];
  const float* HRUim = (const float*)d_in[3];
  const float* HBUre = (const float*)d_in[4];
  const float* HBUim = (const float*)d_in[5];
  const float* nre   = (const float*)d_in[6];
  const float* nim   = (const float*)d_in[7];
  const float* P1    = (const float*)d_in[8];
  const float* P2    = (const float*)d_in[9];
  const float* PT    = (const float*)d_in[10];
  const float* SA    = (const float*)d_in[11];
  const float* ST    = (const float*)d_in[12];
  const float* wv_w  = (const float*)d_in[13];
  const float* wv_b  = (const float*)d_in[14];
  const float* wq_w  = (const float*)d_in[15];
  const float* wq_b  = (const float*)d_in[16];
  const float* wz_w  = (const float*)d_in[17];
  const float* wz_b  = (const float*)d_in[18];
  const float* lnw   = (const float*)d_in[19];
  const float* lnb   = (const float*)d_in[20];
  const float* sv_w  = (const float*)d_in[21];
  const float* sv_b  = (const float*)d_in[22];
  const float* sq_w  = (const float*)d_in[23];
  const float* sq_b  = (const float*)d_in[24];

  float* ws  = (float*)d_ws;
  float* tre = ws + OFF_THRE;
  float* tim = ws + OFF_THIM;
  float* fre = ws + OFF_FRE;
  float* fim = ws + OFF_FIM;
  float* wt  = ws + OFF_WT;
  float* y0  = ws + OFF_Y0;
  float* xb  = ws + OFF_X;

  k_theta<<<2048, 256, 0, stream>>>(P1, P2, PT, tre, tim);
  k_F<<<2048, 256, 0, stream>>>(SA, ST, fre, fim);
  k_W<<<2048, 512, 0, stream>>>(HBRre, HBRim, fre, fim, tre, tim, wt);
  k_y0<<<512, 256, 0, stream>>>(HRUre, HRUim, wt, y0);
  k_fin<<<2048, 256, 0, stream>>>(HBUre, HBUim, fre, fim, y0, nre, nim, xb);
  k_psa<<<16, 256, 0, stream>>>(xb, wv_w, wv_b, wq_w, wq_b, wz_w, wz_b,
                                lnw, lnb, sv_w, sv_b, sq_w, sq_b, (float*)d_out);
}

// Round 2
// 145.337 us; speedup vs baseline: 2.1132x; 2.1132x over previous
//
#include <hip/hip_runtime.h>
#include <math.h>

// dims: B=16 K=1 NC=64 NR=4 RF=4 L=8 M=256 N=1024 BS_TDD=16 RIS_TDD=16
static constexpr double TWO_PI_D = 6.283185307179586476925287;

// workspace offsets (floats)
static constexpr size_t OFF_THRE = 0;          // theta_re [l][c][n]      524288
static constexpr size_t OFF_THIM = 524288;     // theta_im                524288
static constexpr size_t OFF_FBF  = 1048576;    // F bf16 [c][comp][lf][m] 1048576 shorts = 524288 floats
static constexpr size_t OFF_WT   = 1572864;    // WT [l][c][n][f][2]      4194304
static constexpr size_t OFF_Y0   = 5767168;    // y0 [b][l][c][rf][2]     262144
static constexpr size_t OFF_X    = 6029312;    // x  [b][c][rf][t]        262144
static constexpr size_t WS_FLOATS = 6291456;   // 25.2 MB

typedef __attribute__((ext_vector_type(8))) short short8;
typedef __attribute__((ext_vector_type(4))) float f32x4;

__device__ __forceinline__ double fm_of(int c){
  return ((double)(c + 1) - 32.5) * (1.0e9 / 64.0) + 1.0e11;
}
__device__ __forceinline__ unsigned short f2bf(float x){
  unsigned int u = __float_as_uint(x);
  return (unsigned short)((u + 0x7FFFu + ((u >> 16) & 1u)) >> 16);
}
__device__ __forceinline__ float bf2f(unsigned short h){
  return __uint_as_float(((unsigned int)h) << 16);
}

__global__ __launch_bounds__(256) void k_theta(
    const float* __restrict__ P1, const float* __restrict__ P2,
    const float* __restrict__ PT, float* __restrict__ tre, float* __restrict__ tim)
{
  int t = blockIdx.x * 256 + threadIdx.x;       // (l*64+c)*1024+n
  int n = t & 1023, c = (t >> 10) & 63, l = t >> 16;
  float p1 = P1[l * 1024 + n], p2 = P2[l * 1024 + n];
  const float TWO_PI_F = 6.2831855f, SEG_F = 3.1415927f;
  int k1 = (int)floorf((TWO_PI_F * p1) / SEG_F);   // BIT=1 -> seg=pi -> exp(i*k*pi)=+-1
  int k2 = (int)floorf((TWO_PI_F * p2) / SEG_F);
  float s = ((k1 + k2) & 1) ? -1.f : 1.f;
  float a1 = 5.0e-9f / (1.f + expf(-PT[l * 16 + (n >> 6)]));  // MAX_DELAY*sigmoid
  double arg = TWO_PI_D * fm_of(c) * (double)a1;
  double sa, ca;
  sincos(arg, &sa, &ca);
  tre[t] = s * (float)ca;
  tim[t] = s * (float)sa;
}

// F -> bf16, layout [c][comp][lf=l*4+f][m]
__global__ __launch_bounds__(256) void k_F(
    const float* __restrict__ SA, const float* __restrict__ ST,
    unsigned short* __restrict__ Fbf)
{
  int t = blockIdx.x * 256 + threadIdx.x;       // ((l*64+c)*4+f)*256+m
  int m = t & 255, f = (t >> 8) & 3, c = (t >> 10) & 63, l = t >> 16;
  float sa_ = SA[(size_t)((l * 64 + c) * 256 + m) * 4 + f];       // S_analog [L][NC][M][RF]
  float st_ = ST[((l * 64 + c) * 16 + (m >> 4)) * 4 + f];         // S_TDD [L][NC][16][RF]
  float bdel = 5.0e-9f / (1.f + expf(-st_));
  double ang = (double)sa_ + TWO_PI_D * fm_of(c) * (double)bdel;
  double sn, cs;
  sincos(ang, &sn, &cs);
  size_t base = ((size_t)(c * 2) * 32 + (l * 4 + f)) * 256 + m;
  Fbf[base]        = f2bf((float)cs * 0.0625f);   // re
  Fbf[base + 8192] = f2bf((float)sn * 0.0625f);   // im (comp stride 32*256)
}

// WT[l,c,n,f] = theta[l,c,n] * sum_m H_BR[c,n,m] * F[l,c,m,f]   (bf16 MFMA GEMM)
// grid 256 = (c, n-chunk of 256). 512 thr = 8 waves: wave w -> lftile=w&1, ng=w>>1.
__global__ __launch_bounds__(512) void k_W(
    const float* __restrict__ Hre, const float* __restrict__ Him,
    const unsigned short* __restrict__ Fbf,
    const float* __restrict__ tre, const float* __restrict__ tim,
    float* __restrict__ WT)
{
  __shared__ __align__(16) short lA[2][2][256][32];   // 64 KB, row=64B, 16B-granule XOR (n&3)
  __shared__ __align__(16) short lB[2][2][32][32];    // 8 KB,  row=64B, XOR (lf&3)
  const int bid = blockIdx.x;
  const int c = bid >> 2, n0 = (bid & 3) * 256;
  const int tid = threadIdx.x;
  const int lane = tid & 63, w = tid >> 6;
  const int lftile = w & 1, ng = w >> 1;
  const int kq = lane >> 4, rm = lane & 15;
  const int s_mq = tid & 7, s_nr = tid >> 3;                         // A staging
  const int b_comp = tid >> 7, b_lf = (tid >> 2) & 31, b_q = tid & 3; // B staging (tid<256)

  f32x4 accRe[4], accIm[4];
  #pragma unroll
  for (int i = 0; i < 4; i++){
    accRe[i] = (f32x4){0.f, 0.f, 0.f, 0.f};
    accIm[i] = (f32x4){0.f, 0.f, 0.f, 0.f};
  }

  float4 sRe[4], sIm[4];
  short8 sB;

  auto LOADC = [&](int ck){
    size_t m0 = (size_t)ck * 32;
    #pragma unroll
    for (int p = 0; p < 4; p++){
      int n = p * 64 + s_nr;
      size_t g = ((size_t)c * 1024 + n0 + n) * 256 + m0 + s_mq * 4;
      sRe[p] = *(const float4*)(Hre + g);
      sIm[p] = *(const float4*)(Him + g);
    }
    if (tid < 256){
      size_t gb = ((size_t)(c * 2 + b_comp) * 32 + b_lf) * 256 + m0 + b_q * 8;
      sB = *(const short8*)(Fbf + gb);
    }
  };
  auto WRITEC = [&](int buf){
    #pragma unroll
    for (int p = 0; p < 4; p++){
      int n = p * 64 + s_nr;
      int eo = (((s_mq >> 1) ^ (n & 3)) << 3) + (s_mq & 1) * 4;
      unsigned int r0 = (unsigned)f2bf(sRe[p].x) | ((unsigned)f2bf(sRe[p].y) << 16);
      unsigned int r1 = (unsigned)f2bf(sRe[p].z) | ((unsigned)f2bf(sRe[p].w) << 16);
      *(uint2*)&lA[buf][0][n][eo] = make_uint2(r0, r1);
      unsigned int i0 = (unsigned)f2bf(sIm[p].x) | ((unsigned)f2bf(sIm[p].y) << 16);
      unsigned int i1 = (unsigned)f2bf(sIm[p].z) | ((unsigned)f2bf(sIm[p].w) << 16);
      *(uint2*)&lA[buf][1][n][eo] = make_uint2(i0, i1);
    }
    if (tid < 256){
      *(short8*)&lB[buf][b_comp][b_lf][(b_q ^ (b_lf & 3)) << 3] = sB;
    }
  };
  auto COMPUTE = [&](int buf){
    int col = lftile * 16 + rm;
    int be = (kq ^ (col & 3)) << 3;
    short8 bRe = *(const short8*)&lB[buf][0][col][be];
    short8 bIm = *(const short8*)&lB[buf][1][col][be];
    short8 bImN;
    #pragma unroll
    for (int i = 0; i < 8; i++) bImN[i] = bIm[i] ^ (short)0x8000;
    #pragma unroll
    for (int nt = 0; nt < 4; nt++){
      int n = ng * 64 + nt * 16 + rm;
      int eo = (kq ^ (n & 3)) << 3;
      short8 are = *(const short8*)&lA[buf][0][n][eo];
      short8 aim = *(const short8*)&lA[buf][1][n][eo];
      accRe[nt] = __builtin_amdgcn_mfma_f32_16x16x32_bf16(are, bRe,  accRe[nt], 0, 0, 0);
      accRe[nt] = __builtin_amdgcn_mfma_f32_16x16x32_bf16(aim, bImN, accRe[nt], 0, 0, 0);
      accIm[nt] = __builtin_amdgcn_mfma_f32_16x16x32_bf16(are, bIm,  accIm[nt], 0, 0, 0);
      accIm[nt] = __builtin_amdgcn_mfma_f32_16x16x32_bf16(aim, bRe,  accIm[nt], 0, 0, 0);
    }
  };

  LOADC(0); WRITEC(0); __syncthreads();
  for (int ck = 0; ck < 8; ck++){
    int buf = ck & 1;
    if (ck < 7) LOADC(ck + 1);
    COMPUTE(buf);
    if (ck < 7) WRITEC(buf ^ 1);
    __syncthreads();
  }

  // epilogue: theta-multiply + store. C-layout: col=lane&15 (lf), row=(lane>>4)*4+r (n)
  #pragma unroll
  for (int nt = 0; nt < 4; nt++){
    #pragma unroll
    for (int r = 0; r < 4; r++){
      int n = n0 + ng * 64 + nt * 16 + kq * 4 + r;
      int lf = lftile * 16 + rm;
      int l = lf >> 2, f = lf & 3;
      size_t ti = (size_t)(l * 64 + c) * 1024 + n;
      float wr = tre[ti], wi = tim[ti];
      float xr = accRe[nt][r], xi = accIm[nt][r];
      float2 o;
      o.x = wr * xr - wi * xi;
      o.y = wr * xi + wi * xr;
      *(float2*)(WT + ti * 8 + f * 2) = o;
    }
  }
}

// y0[b,l,c,r,f] = sum_n H_RU[b,c,r,n] * WT[l,c,n,f]
__global__ __launch_bounds__(256) void k_y0(
    const float* __restrict__ Rre, const float* __restrict__ Rim,
    const float* __restrict__ WT, float* __restrict__ Y0)
{
  __shared__ __align__(16) float wt[8192];
  int bid = blockIdx.x;
  int lidx = (bid & 7) * 64 + (bid >> 3);     // same-c blocks co-XCD (H_RU L2 reuse over l)
  int c = lidx >> 3, l = lidx & 7;
  const float* src = WT + (size_t)(l * 64 + c) * 8192;
  #pragma unroll
  for (int kk = 0; kk < 8; kk++){
    int i = (threadIdx.x + 256 * kk) * 4;
    *(float4*)(wt + i) = *(const float4*)(src + i);
  }
  __syncthreads();
  int tid = threadIdx.x;
  int q = tid & 3, r = (tid >> 2) & 3, b = tid >> 4;
  const float* hr = Rre + ((size_t)((b * 64 + c) * 4 + r)) * 1024;
  const float* hi = Rim + ((size_t)((b * 64 + c) * 4 + r)) * 1024;
  float aR[4] = {0,0,0,0}, aI[4] = {0,0,0,0};
  #pragma unroll 4
  for (int i = 0; i < 256; i++){
    int n = i * 4 + q;
    float xr = hr[n], xi = hi[n];
    float4 w01 = *(const float4*)(wt + n * 8);
    float4 w23 = *(const float4*)(wt + n * 8 + 4);
    aR[0] += xr * w01.x - xi * w01.y;  aI[0] += xr * w01.y + xi * w01.x;
    aR[1] += xr * w01.z - xi * w01.w;  aI[1] += xr * w01.w + xi * w01.z;
    aR[2] += xr * w23.x - xi * w23.y;  aI[2] += xr * w23.y + xi * w23.x;
    aR[3] += xr * w23.z - xi * w23.w;  aI[3] += xr * w23.w + xi * w23.z;
  }
  #pragma unroll
  for (int s = 1; s < 4; s <<= 1){
    #pragma unroll
    for (int ff = 0; ff < 4; ff++){
      aR[ff] += __shfl_xor(aR[ff], s);
      aI[ff] += __shfl_xor(aI[ff], s);
    }
  }
  if (q == 0){
    float* dst = Y0 + ((size_t)((b * 8 + l) * 64 + c) * 16 + r * 4) * 2;
    float4 o0; o0.x = aR[0]; o0.y = aI[0]; o0.z = aR[1]; o0.w = aI[1];
    float4 o1; o1.x = aR[2]; o1.y = aI[2]; o1.z = aR[3]; o1.w = aI[3];
    *(float4*)(dst)     = o0;
    *(float4*)(dst + 4) = o1;
  }
}

// per (b,l,c) wave: y0 += H_BU*F ; power; noise; scatter into x[b,c,rf,t]
__global__ __launch_bounds__(256) void k_fin(
    const float* __restrict__ Ure, const float* __restrict__ Uim,
    const unsigned short* __restrict__ Fbf,
    const float* __restrict__ Y0, const float* __restrict__ nre, const float* __restrict__ nim,
    float* __restrict__ X)
{
  int wid = blockIdx.x * 4 + (threadIdx.x >> 6);  // 8192 = (b,l,c)
  int lane = threadIdx.x & 63;
  int c = wid & 63, l = (wid >> 6) & 7, b = wid >> 9;
  int pair = lane >> 2, q = lane & 3;
  int r = pair >> 2, f = pair & 3;
  const float* ur = Ure + ((size_t)((b * 64 + c) * 4 + r)) * 256;
  const float* ui = Uim + ((size_t)((b * 64 + c) * 4 + r)) * 256;
  const unsigned short* fb = Fbf + ((size_t)(c * 2) * 32 + (l * 4 + f)) * 256;
  float sR = 0.f, sI = 0.f;
  #pragma unroll 4
  for (int mm = 0; mm < 64; mm++){
    int m = q * 64 + mm;
    float ar = ur[m], ai = ui[m];
    float br = bf2f(fb[m]), bi = bf2f(fb[m + 8192]);
    sR += ar * br - ai * bi;
    sI += ar * bi + ai * br;
  }
  sR += __shfl_xor(sR, 1); sI += __shfl_xor(sI, 1);
  sR += __shfl_xor(sR, 2); sI += __shfl_xor(sI, 2);
  float2 y0 = *(const float2*)(Y0 + ((size_t)((b * 8 + l) * 64 + c) * 16 + pair) * 2);
  float yR = y0.x + sR, yI = y0.y + sI;
  float p = yR * yR + yI * yI;
  p += __shfl_xor(p, 4); p += __shfl_xor(p, 8);
  p += __shfl_xor(p, 16); p += __shfl_xor(p, 32);
  float sc = sqrtf(p * 0.05f);                 // sqrt(power * snr_lin/2), snr_lin=0.1
  if (q == 0){
    size_t ni = ((size_t)((b * 8 + l) * 64 + c) * 4 + r) * 4 + f;
    float oR = yR + nre[ni] * sc;
    float oI = yI + nim[ni] * sc;
    size_t xb = ((size_t)(b * 64 + c) * 16 + pair) * 16;
    X[xb + l]     = oR;   // t = l      (real half)
    X[xb + 8 + l] = oI;   // t = 8 + l  (imag half)
  }
}

// Parallel Polarized Self-Attention, one block per b. b=16,c=64,hw=256.
__global__ __launch_bounds__(256) void k_psa(
    const float* __restrict__ Xin,
    const float* __restrict__ wv_w, const float* __restrict__ wv_b,
    const float* __restrict__ wq_w, const float* __restrict__ wq_b,
    const float* __restrict__ wz_w, const float* __restrict__ wz_b,
    const float* __restrict__ lnw, const float* __restrict__ lnb,
    const float* __restrict__ sv_w, const float* __restrict__ sv_b,
    const float* __restrict__ sq_w, const float* __restrict__ sq_b,
    float* __restrict__ out)
{
  __shared__ float x[64 * 257];
  __shared__ float buf[256];
  __shared__ float xms[64], xqs[64], chw[64], wcomb[64];
  __shared__ float cwzs[32], swqs[32];
  __shared__ float red4[8];
  int b = blockIdx.x, tid = threadIdx.x;
  const float* xin = Xin + (size_t)b * 16384;
  for (int kk = 0; kk < 64; kk++){
    int i = tid + 256 * kk;
    x[(i >> 8) * 257 + (i & 255)] = xin[i];
  }
  __syncthreads();
  if (tid < 64){                                 // row means
    float s = 0.f;
    for (int n = 0; n < 256; n++) s += x[tid * 257 + n];
    xms[tid] = s * (1.f / 256.f);
  }
  // channel softmax over n
  float lq = wq_b[0];
  for (int cc = 0; cc < 64; cc++) lq += wq_w[cc] * x[cc * 257 + tid];
  float mx = lq;
  for (int s = 1; s < 64; s <<= 1) mx = fmaxf(mx, __shfl_xor(mx, s));
  if ((tid & 63) == 0) red4[tid >> 6] = mx;
  __syncthreads();
  mx = fmaxf(fmaxf(red4[0], red4[1]), fmaxf(red4[2], red4[3]));
  float e = expf(lq - mx);
  float se = e;
  for (int s = 1; s < 64; s <<= 1) se += __shfl_xor(se, s);
  if ((tid & 63) == 0) red4[4 + (tid >> 6)] = se;
  __syncthreads();
  se = red4[4] + red4[5] + red4[6] + red4[7];
  buf[tid] = e / se;                             // cwq[n]
  __syncthreads();
  if (tid < 64){                                 // xq[c] = sum_n x*cwq
    float s = 0.f;
    for (int n = 0; n < 256; n++) s += x[tid * 257 + n] * buf[n];
    xqs[tid] = s;
  }
  __syncthreads();
  if (tid < 32){                                 // cwz[k]
    float s = wv_b[tid];
    for (int cc = 0; cc < 64; cc++) s += wv_w[tid * 64 + cc] * xqs[cc];
    cwzs[tid] = s;
  }
  __syncthreads();
  if (tid < 64){                                 // z, LayerNorm, sigmoid
    float z = wz_b[tid];
    for (int k = 0; k < 32; k++) z += cwzs[k] * wz_w[tid * 32 + k];
    float s1 = z, s2 = z * z;
    for (int s = 1; s < 64; s <<= 1){ s1 += __shfl_xor(s1, s); s2 += __shfl_xor(s2, s); }
    float mu = s1 * (1.f / 64.f);
    float var = s2 * (1.f / 64.f) - mu * mu;
    float zn = (z - mu) * rsqrtf(var + 1e-5f) * lnw[tid] + lnb[tid];
    chw[tid] = 1.f / (1.f + expf(-zn));
  }
  if (tid < 32){                                 // spatial softmax over k
    float s = sq_b[tid];
    for (int cc = 0; cc < 64; cc++) s += sq_w[tid * 64 + cc] * xms[cc];
    float m2 = s;
    for (int st = 1; st < 32; st <<= 1) m2 = fmaxf(m2, __shfl_xor(m2, st));
    float ee = expf(s - m2), ss = ee;
    for (int st = 1; st < 32; st <<= 1) ss += __shfl_xor(ss, st);
    swqs[tid] = ee / ss;
  }
  __syncthreads();
  if (tid < 64){                                 // wcomb[c] = sum_k swq*sv_w
    float s = 0.f;
    for (int k = 0; k < 32; k++) s += swqs[k] * sv_w[k * 64 + tid];
    wcomb[tid] = s;
  }
  __syncthreads();
  float bcomb = 0.f;
  for (int k = 0; k < 32; k++) bcomb += swqs[k] * sv_b[k];
  float sz = bcomb;
  for (int cc = 0; cc < 64; cc++) sz += wcomb[cc] * x[cc * 257 + tid];
  float spw = 1.f / (1.f + expf(-sz));
  buf[tid] = spw;                                // reuse buf (cwq dead)
  __syncthreads();
  for (int kk = 0; kk < 64; kk++){
    int i = tid + 256 * kk;
    int cc = i >> 8, n = i & 255;
    out[(size_t)b * 16384 + i] = (buf[n] + chw[cc]) * x[cc * 257 + n];
  }
}

extern "C" void kernel_launch(void* const* d_in, const int* in_sizes, int n_in,
                              void* d_out, int out_size, void* d_ws, size_t ws_size,
                              hipStream_t stream)
{
  if (ws_size < WS_FLOATS * sizeof(float)) return;  // loud failure via validation
  const float* HBRre = (const float*)d_in[0];
  const float* HBRim = (const float*)d_in[1];
  const float* HRUre = (const float*)d_in[2];
  const float* HRUim = (const float*)d_in[3];
  const float* HBUre = (const float*)d_in[4];
  const float* HBUim = (const float*)d_in[5];
  const float* nre   = (const float*)d_in[6];
  const float* nim   = (const float*)d_in[7];
  const float* P1    = (const float*)d_in[8];
  const float* P2    = (const float*)d_in[9];
  const float* PT    = (const float*)d_in[10];
  const float* SA    = (const float*)d_in[11];
  const float* ST    = (const float*)d_in[12];
  const float* wv_w  = (const float*)d_in[13];
  const float* wv_b  = (const float*)d_in[14];
  const float* wq_w  = (const float*)d_in[15];
  const float* wq_b  = (const float*)d_in[16];
  const float* wz_w  = (const float*)d_in[17];
  const float* wz_b  = (const float*)d_in[18];
  const float* lnw   = (const float*)d_in[19];
  const float* lnb   = (const float*)d_in[20];
  const float* sv_w  = (const float*)d_in[21];
  const float* sv_b  = (const float*)d_in[22];
  const float* sq_w  = (const float*)d_in[23];
  const float* sq_b  = (const float*)d_in[24];

  float* ws  = (float*)d_ws;
  float* tre = ws + OFF_THRE;
  float* tim = ws + OFF_THIM;
  unsigned short* fbf = (unsigned short*)(ws + OFF_FBF);
  float* wt  = ws + OFF_WT;
  float* y0  = ws + OFF_Y0;
  float* xb  = ws + OFF_X;

  k_theta<<<2048, 256, 0, stream>>>(P1, P2, PT, tre, tim);
  k_F<<<2048, 256, 0, stream>>>(SA, ST, fbf);
  k_W<<<256, 512, 0, stream>>>(HBRre, HBRim, fbf, tre, tim, wt);
  k_y0<<<512, 256, 0, stream>>>(HRUre, HRUim, wt, y0);
  k_fin<<<2048, 256, 0, stream>>>(HBUre, HBUim, fbf, y0, nre, nim, xb);
  k_psa<<<16, 256, 0, stream>>>(xb, wv_w, wv_b, wq_w, wq_b, wz_w, wz_b,
                                lnw, lnb, sv_w, sv_b, sq_w, sq_b, (float*)d_out);
}

// Round 3
// 61.751 us; speedup vs baseline: 4.9737x; 2.3536x over previous
//
#include <hip/hip_runtime.h>
#include <math.h>

// dims: B=16 K=1 NC=64 NR=4 RF=4 L=8 M=256 N=1024 BS_TDD=16 RIS_TDD=16
static constexpr double TWO_PI_D = 6.283185307179586476925287;

// workspace offsets (floats)
static constexpr size_t OFF_THRE = 0;          // theta_re [l][c][n]          524288
static constexpr size_t OFF_THIM = 524288;     // theta_im                    524288
static constexpr size_t OFF_FBF  = 1048576;    // F bf16 [c][comp][lf][m]     1048576 shorts
static constexpr size_t OFF_WTBF = 1572864;    // WT bf16 [c][comp][lf][n]    4194304 shorts
static constexpr size_t OFF_Y0P  = 3670016;    // y0 partials [5][c][row][lf][2] 1310720
static constexpr size_t OFF_X    = 4980736;    // x [b][c][rf][t]             262144
static constexpr size_t WS_FLOATS = 5242880;   // 21 MB

typedef __attribute__((ext_vector_type(8))) short short8;
typedef __attribute__((ext_vector_type(4))) float f32x4;

__device__ __forceinline__ double fm_of(int c){
  return ((double)(c + 1) - 32.5) * (1.0e9 / 64.0) + 1.0e11;
}
__device__ __forceinline__ unsigned short f2bf(float x){
  unsigned int u = __float_as_uint(x);
  return (unsigned short)((u + 0x7FFFu + ((u >> 16) & 1u)) >> 16);
}

// theta (+-1 sign * TTD phase) and F (exp(i SA)/16 * TTD phase), TTD sincos via LDS table
__global__ __launch_bounds__(256) void k_prep(
    const float* __restrict__ P1, const float* __restrict__ P2,
    const float* __restrict__ PT, const float* __restrict__ SA,
    const float* __restrict__ ST,
    float* __restrict__ tre, float* __restrict__ tim, unsigned short* __restrict__ Fbf)
{
  __shared__ double tcs[16], tsn[16];
  int bid = blockIdx.x, tid = threadIdx.x;
  const float TWO_PI_F = 6.2831855f, SEG_F = 3.1415927f;
  if (bid < 2048){                                   // theta: (l,c, n-quarter)
    int l = bid >> 8, c = (bid >> 2) & 63, n0 = (bid & 3) * 256;
    if (tid < 4){
      int ris = (n0 >> 6) + tid;
      double a1 = 5.0e-9 / (1.0 + exp((double)(-PT[l * 16 + ris])));
      sincos(TWO_PI_D * fm_of(c) * a1, &tsn[tid], &tcs[tid]);
    }
    __syncthreads();
    int n = n0 + tid;
    float p1 = P1[l * 1024 + n], p2 = P2[l * 1024 + n];
    int k1 = (int)floorf((TWO_PI_F * p1) / SEG_F);   // BIT=1 -> exp(i*k*pi)=+-1
    int k2 = (int)floorf((TWO_PI_F * p2) / SEG_F);
    float s = ((k1 + k2) & 1) ? -1.f : 1.f;
    int t = (l * 64 + c) * 1024 + n;
    int ti = tid >> 6;
    tre[t] = s * (float)tcs[ti];
    tim[t] = s * (float)tsn[ti];
  } else {                                           // F: (l,c,f) x m
    int bid2 = bid - 2048;
    int l = bid2 >> 8, c = (bid2 >> 2) & 63, f = bid2 & 3;
    int m = tid;
    if (tid < 16){
      double bdel = 5.0e-9 / (1.0 + exp((double)(-ST[((l * 64 + c) * 16 + tid) * 4 + f])));
      sincos(TWO_PI_D * fm_of(c) * bdel, &tsn[tid], &tcs[tid]);
    }
    __syncthreads();
    float sa_ = SA[(size_t)((l * 64 + c) * 256 + m) * 4 + f];
    float ssa, csa;
    sincosf(sa_, &ssa, &csa);                        // exact split: exp(iSA)*exp(i2pi f tau)
    float cb = (float)tcs[m >> 4], sb = (float)tsn[m >> 4];
    size_t base = ((size_t)(c * 2) * 32 + (l * 4 + f)) * 256 + m;
    Fbf[base]        = f2bf((csa * cb - ssa * sb) * 0.0625f);
    Fbf[base + 8192] = f2bf((csa * sb + ssa * cb) * 0.0625f);
  }
}

// WT[c,comp,lf,n] (bf16) = theta[l,c,n] * sum_m H_BR[c,n,m] * F[l,c,m,f]   (bf16 MFMA)
// grid 256 = (c, n-chunk of 256). 512 thr = 8 waves: wave w -> lftile=w&1, ng=w>>1.
__global__ __launch_bounds__(512) void k_W(
    const float* __restrict__ Hre, const float* __restrict__ Him,
    const unsigned short* __restrict__ Fbf,
    const float* __restrict__ tre, const float* __restrict__ tim,
    unsigned short* __restrict__ WTbf)
{
  __shared__ __align__(16) short lA[2][2][256][32];   // 64 KB, 16B-granule XOR (n&3)
  __shared__ __align__(16) short lB[2][2][32][32];    // 8 KB,  XOR (lf&3)
  const int bid = blockIdx.x;
  const int c = bid >> 2, n0 = (bid & 3) * 256;
  const int tid = threadIdx.x;
  const int lane = tid & 63, w = tid >> 6;
  const int lftile = w & 1, ng = w >> 1;
  const int kq = lane >> 4, rm = lane & 15;
  const int s_mq = tid & 7, s_nr = tid >> 3;                          // A staging
  const int b_comp = tid >> 7, b_lf = (tid >> 2) & 31, b_q = tid & 3; // B staging (tid<256)

  f32x4 accRe[4], accIm[4];
  #pragma unroll
  for (int i = 0; i < 4; i++){
    accRe[i] = (f32x4){0.f, 0.f, 0.f, 0.f};
    accIm[i] = (f32x4){0.f, 0.f, 0.f, 0.f};
  }
  float4 sRe[4], sIm[4];
  short8 sB;

  auto LOADC = [&](int ck){
    size_t m0 = (size_t)ck * 32;
    #pragma unroll
    for (int p = 0; p < 4; p++){
      int n = p * 64 + s_nr;
      size_t g = ((size_t)c * 1024 + n0 + n) * 256 + m0 + s_mq * 4;
      sRe[p] = *(const float4*)(Hre + g);
      sIm[p] = *(const float4*)(Him + g);
    }
    if (tid < 256){
      size_t gb = ((size_t)(c * 2 + b_comp) * 32 + b_lf) * 256 + m0 + b_q * 8;
      sB = *(const short8*)(Fbf + gb);
    }
  };
  auto WRITEC = [&](int buf){
    #pragma unroll
    for (int p = 0; p < 4; p++){
      int n = p * 64 + s_nr;
      int eo = (((s_mq >> 1) ^ (n & 3)) << 3) + (s_mq & 1) * 4;
      unsigned int r0 = (unsigned)f2bf(sRe[p].x) | ((unsigned)f2bf(sRe[p].y) << 16);
      unsigned int r1 = (unsigned)f2bf(sRe[p].z) | ((unsigned)f2bf(sRe[p].w) << 16);
      *(uint2*)&lA[buf][0][n][eo] = make_uint2(r0, r1);
      unsigned int i0 = (unsigned)f2bf(sIm[p].x) | ((unsigned)f2bf(sIm[p].y) << 16);
      unsigned int i1 = (unsigned)f2bf(sIm[p].z) | ((unsigned)f2bf(sIm[p].w) << 16);
      *(uint2*)&lA[buf][1][n][eo] = make_uint2(i0, i1);
    }
    if (tid < 256){
      *(short8*)&lB[buf][b_comp][b_lf][(b_q ^ (b_lf & 3)) << 3] = sB;
    }
  };
  auto COMPUTE = [&](int buf){
    int col = lftile * 16 + rm;
    int be = (kq ^ (col & 3)) << 3;
    short8 bRe = *(const short8*)&lB[buf][0][col][be];
    short8 bIm = *(const short8*)&lB[buf][1][col][be];
    short8 bImN;
    #pragma unroll
    for (int i = 0; i < 8; i++) bImN[i] = bIm[i] ^ (short)0x8000;
    #pragma unroll
    for (int nt = 0; nt < 4; nt++){
      int n = ng * 64 + nt * 16 + rm;
      int eo = (kq ^ (n & 3)) << 3;
      short8 are = *(const short8*)&lA[buf][0][n][eo];
      short8 aim = *(const short8*)&lA[buf][1][n][eo];
      accRe[nt] = __builtin_amdgcn_mfma_f32_16x16x32_bf16(are, bRe,  accRe[nt], 0, 0, 0);
      accRe[nt] = __builtin_amdgcn_mfma_f32_16x16x32_bf16(aim, bImN, accRe[nt], 0, 0, 0);
      accIm[nt] = __builtin_amdgcn_mfma_f32_16x16x32_bf16(are, bIm,  accIm[nt], 0, 0, 0);
      accIm[nt] = __builtin_amdgcn_mfma_f32_16x16x32_bf16(aim, bRe,  accIm[nt], 0, 0, 0);
    }
  };

  LOADC(0); WRITEC(0); __syncthreads();
  for (int ck = 0; ck < 8; ck++){
    int buf = ck & 1;
    if (ck < 7) LOADC(ck + 1);
    COMPUTE(buf);
    if (ck < 7) WRITEC(buf ^ 1);
    __syncthreads();
  }

  // epilogue: theta-multiply, pack bf16, store to WT[c][comp][lf][n]
  const int lf = lftile * 16 + rm;
  const int l = lf >> 2;
  #pragma unroll
  for (int nt = 0; nt < 4; nt++){
    int nb = n0 + ng * 64 + nt * 16 + kq * 4;
    unsigned short pr[4], pi_[4];
    #pragma unroll
    for (int r = 0; r < 4; r++){
      size_t ti = (size_t)(l * 64 + c) * 1024 + nb + r;
      float wr = tre[ti], wi = tim[ti];
      float xr = accRe[nt][r], xi = accIm[nt][r];
      pr[r]  = f2bf(wr * xr - wi * xi);
      pi_[r] = f2bf(wr * xi + wi * xr);
    }
    size_t rb = ((size_t)(c * 2) * 32 + lf) * 1024 + nb;
    *(uint2*)(WTbf + rb) =
        make_uint2((unsigned)pr[0] | ((unsigned)pr[1] << 16),
                   (unsigned)pr[2] | ((unsigned)pr[3] << 16));
    *(uint2*)(WTbf + rb + 32768) =
        make_uint2((unsigned)pi_[0] | ((unsigned)pi_[1] << 16),
                   (unsigned)pi_[2] | ((unsigned)pi_[3] << 16));
  }
}

// Y0p[chunk,c,row=b*4+r,lf] = partial sum: chunks 0-3 = H_RU(n-slice)*WT, chunk 4 = H_BU*F
// grid 320 = (chunk, c). 512 thr = 8 waves: lftile=w&1, mt=w>>1 (16-row M-tile).
__global__ __launch_bounds__(512) void k_y0(
    const float* __restrict__ Rre, const float* __restrict__ Rim,
    const float* __restrict__ Ure, const float* __restrict__ Uim,
    const unsigned short* __restrict__ WTbf, const unsigned short* __restrict__ Fbf,
    float* __restrict__ Y0p)
{
  __shared__ __align__(16) short lA[2][2][64][32];    // 16 KB
  __shared__ __align__(16) short lB[2][2][32][32];    // 8 KB
  const int bid = blockIdx.x;
  const int chunk = bid >> 6, c = bid & 63;
  const int tid = threadIdx.x;
  const int lane = tid & 63, w = tid >> 6;
  const int lftile = w & 1, mt = w >> 1;
  const int kq = lane >> 4, rm = lane & 15;
  const int s_mq = tid & 7, s_nr = tid >> 3;
  const int b_comp = tid >> 7, b_lf = (tid >> 2) & 31, b_q = tid & 3;

  const float* Are; const float* Aim; int ars, ac0;
  const unsigned short* Bb; int brs;
  if (chunk < 4){ Are = Rre; Aim = Rim; ars = 1024; ac0 = chunk * 256; Bb = WTbf; brs = 1024; }
  else          { Are = Ure; Aim = Uim; ars = 256;  ac0 = 0;           Bb = Fbf;  brs = 256;  }
  const size_t arow = ((size_t)((s_nr >> 2) * 64 + c) * 4 + (s_nr & 3)) * ars + ac0;

  f32x4 accRe = {0.f,0.f,0.f,0.f}, accIm = {0.f,0.f,0.f,0.f};
  float4 sRe, sIm; short8 sB;

  auto LOADC = [&](int ck){
    size_t g = arow + ck * 32 + s_mq * 4;
    sRe = *(const float4*)(Are + g);
    sIm = *(const float4*)(Aim + g);
    if (tid < 256){
      size_t gb = ((size_t)(c * 2 + b_comp) * 32 + b_lf) * brs + ac0 + ck * 32 + b_q * 8;
      sB = *(const short8*)(Bb + gb);
    }
  };
  auto WRITEC = [&](int buf){
    int eo = (((s_mq >> 1) ^ (s_nr & 3)) << 3) + (s_mq & 1) * 4;
    unsigned int r0 = (unsigned)f2bf(sRe.x) | ((unsigned)f2bf(sRe.y) << 16);
    unsigned int r1 = (unsigned)f2bf(sRe.z) | ((unsigned)f2bf(sRe.w) << 16);
    *(uint2*)&lA[buf][0][s_nr][eo] = make_uint2(r0, r1);
    unsigned int i0 = (unsigned)f2bf(sIm.x) | ((unsigned)f2bf(sIm.y) << 16);
    unsigned int i1 = (unsigned)f2bf(sIm.z) | ((unsigned)f2bf(sIm.w) << 16);
    *(uint2*)&lA[buf][1][s_nr][eo] = make_uint2(i0, i1);
    if (tid < 256){
      *(short8*)&lB[buf][b_comp][b_lf][(b_q ^ (b_lf & 3)) << 3] = sB;
    }
  };
  auto COMPUTE = [&](int buf){
    int col = lftile * 16 + rm;
    int be = (kq ^ (col & 3)) << 3;
    short8 bRe = *(const short8*)&lB[buf][0][col][be];
    short8 bIm = *(const short8*)&lB[buf][1][col][be];
    short8 bImN;
    #pragma unroll
    for (int i = 0; i < 8; i++) bImN[i] = bIm[i] ^ (short)0x8000;
    int row = mt * 16 + rm;
    int eo = (kq ^ (row & 3)) << 3;
    short8 are = *(const short8*)&lA[buf][0][row][eo];
    short8 aim = *(const short8*)&lA[buf][1][row][eo];
    accRe = __builtin_amdgcn_mfma_f32_16x16x32_bf16(are, bRe,  accRe, 0, 0, 0);
    accRe = __builtin_amdgcn_mfma_f32_16x16x32_bf16(aim, bImN, accRe, 0, 0, 0);
    accIm = __builtin_amdgcn_mfma_f32_16x16x32_bf16(are, bIm,  accIm, 0, 0, 0);
    accIm = __builtin_amdgcn_mfma_f32_16x16x32_bf16(aim, bRe,  accIm, 0, 0, 0);
  };

  LOADC(0); WRITEC(0); __syncthreads();
  for (int ck = 0; ck < 8; ck++){
    int buf = ck & 1;
    if (ck < 7) LOADC(ck + 1);
    COMPUTE(buf);
    if (ck < 7) WRITEC(buf ^ 1);
    __syncthreads();
  }

  #pragma unroll
  for (int r = 0; r < 4; r++){
    int row = mt * 16 + kq * 4 + r;
    int lf = lftile * 16 + rm;
    size_t idx = ((size_t)(chunk * 64 + c) * 64 + row) * 32 + lf;
    float2 o; o.x = accRe[r]; o.y = accIm[r];
    *(float2*)(Y0p + idx * 2) = o;
  }
}

// per (b,l,c) wave: sum 5 partials; power; noise; scatter into x[b,c,rf,t]
__global__ __launch_bounds__(256) void k_fin(
    const float* __restrict__ Y0p,
    const float* __restrict__ nre, const float* __restrict__ nim,
    float* __restrict__ X)
{
  int wid = blockIdx.x * 4 + (threadIdx.x >> 6);  // 8192 = (b,l,c)
  int lane = threadIdx.x & 63;
  int c = wid & 63, l = (wid >> 6) & 7, b = wid >> 9;
  int pair = lane >> 2;
  int r = pair >> 2, f = pair & 3;
  float yR = 0.f, yI = 0.f;
  #pragma unroll
  for (int ch = 0; ch < 5; ch++){
    size_t idx = ((size_t)(ch * 64 + c) * 64 + b * 4 + r) * 32 + l * 4 + f;
    float2 v = *(const float2*)(Y0p + idx * 2);
    yR += v.x; yI += v.y;
  }
  float p = yR * yR + yI * yI;
  p += __shfl_xor(p, 4); p += __shfl_xor(p, 8);
  p += __shfl_xor(p, 16); p += __shfl_xor(p, 32);
  float sc = sqrtf(p * 0.05f);                 // sqrt(power * snr_lin/2), snr_lin=0.1
  if ((lane & 3) == 0){
    size_t ni = ((size_t)((b * 8 + l) * 64 + c) * 4 + r) * 4 + f;
    float oR = yR + nre[ni] * sc;
    float oI = yI + nim[ni] * sc;
    size_t xb = ((size_t)(b * 64 + c) * 16 + pair) * 16;
    X[xb + l]     = oR;   // t = l      (real half)
    X[xb + 8 + l] = oI;   // t = 8 + l  (imag half)
  }
}

// Parallel Polarized Self-Attention, one block per b. b=16,c=64,hw=256.
__global__ __launch_bounds__(256) void k_psa(
    const float* __restrict__ Xin,
    const float* __restrict__ wv_w, const float* __restrict__ wv_b,
    const float* __restrict__ wq_w, const float* __restrict__ wq_b,
    const float* __restrict__ wz_w, const float* __restrict__ wz_b,
    const float* __restrict__ lnw, const float* __restrict__ lnb,
    const float* __restrict__ sv_w, const float* __restrict__ sv_b,
    const float* __restrict__ sq_w, const float* __restrict__ sq_b,
    float* __restrict__ out)
{
  __shared__ float x[64 * 257];
  __shared__ float buf[256];
  __shared__ float xms[64], xqs[64], chw[64], wcomb[64];
  __shared__ float cwzs[32], swqs[32];
  __shared__ float red4[8];
  int b = blockIdx.x, tid = threadIdx.x;
  const float* xin = Xin + (size_t)b * 16384;
  for (int kk = 0; kk < 64; kk++){
    int i = tid + 256 * kk;
    x[(i >> 8) * 257 + (i & 255)] = xin[i];
  }
  __syncthreads();
  if (tid < 64){                                 // row means
    float s = 0.f;
    for (int n = 0; n < 256; n++) s += x[tid * 257 + n];
    xms[tid] = s * (1.f / 256.f);
  }
  // channel softmax over n
  float lq = wq_b[0];
  for (int cc = 0; cc < 64; cc++) lq += wq_w[cc] * x[cc * 257 + tid];
  float mx = lq;
  for (int s = 1; s < 64; s <<= 1) mx = fmaxf(mx, __shfl_xor(mx, s));
  if ((tid & 63) == 0) red4[tid >> 6] = mx;
  __syncthreads();
  mx = fmaxf(fmaxf(red4[0], red4[1]), fmaxf(red4[2], red4[3]));
  float e = expf(lq - mx);
  float se = e;
  for (int s = 1; s < 64; s <<= 1) se += __shfl_xor(se, s);
  if ((tid & 63) == 0) red4[4 + (tid >> 6)] = se;
  __syncthreads();
  se = red4[4] + red4[5] + red4[6] + red4[7];
  buf[tid] = e / se;                             // cwq[n]
  __syncthreads();
  if (tid < 64){                                 // xq[c] = sum_n x*cwq
    float s = 0.f;
    for (int n = 0; n < 256; n++) s += x[tid * 257 + n] * buf[n];
    xqs[tid] = s;
  }
  __syncthreads();
  if (tid < 32){                                 // cwz[k]
    float s = wv_b[tid];
    for (int cc = 0; cc < 64; cc++) s += wv_w[tid * 64 + cc] * xqs[cc];
    cwzs[tid] = s;
  }
  __syncthreads();
  if (tid < 64){                                 // z, LayerNorm, sigmoid
    float z = wz_b[tid];
    for (int k = 0; k < 32; k++) z += cwzs[k] * wz_w[tid * 32 + k];
    float s1 = z, s2 = z * z;
    for (int s = 1; s < 64; s <<= 1){ s1 += __shfl_xor(s1, s); s2 += __shfl_xor(s2, s); }
    float mu = s1 * (1.f / 64.f);
    float var = s2 * (1.f / 64.f) - mu * mu;
    float zn = (z - mu) * rsqrtf(var + 1e-5f) * lnw[tid] + lnb[tid];
    chw[tid] = 1.f / (1.f + expf(-zn));
  }
  if (tid < 32){                                 // spatial softmax over k
    float s = sq_b[tid];
    for (int cc = 0; cc < 64; cc++) s += sq_w[tid * 64 + cc] * xms[cc];
    float m2 = s;
    for (int st = 1; st < 32; st <<= 1) m2 = fmaxf(m2, __shfl_xor(m2, st));
    float ee = expf(s - m2), ss = ee;
    for (int st = 1; st < 32; st <<= 1) ss += __shfl_xor(ss, st);
    swqs[tid] = ee / ss;
  }
  __syncthreads();
  if (tid < 64){                                 // wcomb[c] = sum_k swq*sv_w
    float s = 0.f;
    for (int k = 0; k < 32; k++) s += swqs[k] * sv_w[k * 64 + tid];
    wcomb[tid] = s;
  }
  __syncthreads();
  float bcomb = 0.f;
  for (int k = 0; k < 32; k++) bcomb += swqs[k] * sv_b[k];
  float sz = bcomb;
  for (int cc = 0; cc < 64; cc++) sz += wcomb[cc] * x[cc * 257 + tid];
  float spw = 1.f / (1.f + expf(-sz));
  buf[tid] = spw;                                // reuse buf (cwq dead)
  __syncthreads();
  for (int kk = 0; kk < 64; kk++){
    int i = tid + 256 * kk;
    int cc = i >> 8, n = i & 255;
    out[(size_t)b * 16384 + i] = (buf[n] + chw[cc]) * x[cc * 257 + n];
  }
}

extern "C" void kernel_launch(void* const* d_in, const int* in_sizes, int n_in,
                              void* d_out, int out_size, void* d_ws, size_t ws_size,
                              hipStream_t stream)
{
  if (ws_size < WS_FLOATS * sizeof(float)) return;  // loud failure via validation
  const float* HBRre = (const float*)d_in[0];
  const float* HBRim = (const float*)d_in[1];
  const float* HRUre = (const float*)d_in[2];
  const float* HRUim = (const float*)d_in[3];
  const float* HBUre = (const float*)d_in[4];
  const float* HBUim = (const float*)d_in[5];
  const float* nre   = (const float*)d_in[6];
  const float* nim   = (const float*)d_in[7];
  const float* P1    = (const float*)d_in[8];
  const float* P2    = (const float*)d_in[9];
  const float* PT    = (const float*)d_in[10];
  const float* SA    = (const float*)d_in[11];
  const float* ST    = (const float*)d_in[12];
  const float* wv_w  = (const float*)d_in[13];
  const float* wv_b  = (const float*)d_in[14];
  const float* wq_w  = (const float*)d_in[15];
  const float* wq_b  = (const float*)d_in[16];
  const float* wz_w  = (const float*)d_in[17];
  const float* wz_b  = (const float*)d_in[18];
  const float* lnw   = (const float*)d_in[19];
  const float* lnb   = (const float*)d_in[20];
  const float* sv_w  = (const float*)d_in[21];
  const float* sv_b  = (const float*)d_in[22];
  const float* sq_w  = (const float*)d_in[23];
  const float* sq_b  = (const float*)d_in[24];

  float* ws  = (float*)d_ws;
  float* tre = ws + OFF_THRE;
  float* tim = ws + OFF_THIM;
  unsigned short* fbf  = (unsigned short*)(ws + OFF_FBF);
  unsigned short* wtbf = (unsigned short*)(ws + OFF_WTBF);
  float* y0p = ws + OFF_Y0P;
  float* xb  = ws + OFF_X;

  k_prep<<<4096, 256, 0, stream>>>(P1, P2, PT, SA, ST, tre, tim, fbf);
  k_W<<<256, 512, 0, stream>>>(HBRre, HBRim, fbf, tre, tim, wtbf);
  k_y0<<<320, 512, 0, stream>>>(HRUre, HRUim, HBUre, HBUim, wtbf, fbf, y0p);
  k_fin<<<2048, 256, 0, stream>>>(y0p, nre, nim, xb);
  k_psa<<<16, 256, 0, stream>>>(xb, wv_w, wv_b, wq_w, wq_b, wz_w, wz_b,
                                lnw, lnb, sv_w, sv_b, sq_w, sq_b, (float*)d_out);
}